// Round 4
// baseline (7469.631 us; speedup 1.0000x reference)
//
#include <hip/hip_runtime.h>

// LIF sim: f32 feed-forward GEMM (scalar-path x, register h-column tiles)
// + block-local f64 scan. Block b owns batch row b; thread n owns neuron n.
constexpr int BSZ = 256;
constexpr int NRN = 512;
constexpr int KIN = 512;
constexpr int TCH = 50;   // timesteps per chunk (f32 acc in registers)
constexpr int NCH = 10;   // 10 * 50 = 500

__global__ __launch_bounds__(512, 2)
void lif_sim(const float* __restrict__ x,
             const float* __restrict__ h1,
             const float* __restrict__ r1,
             float* __restrict__ out)
{
    __shared__ unsigned long long smask[2][8];   // ping-pong 512-bit spike mask

    const int n  = threadIdx.x;   // neuron 0..511
    const int b  = blockIdx.x;    // batch row
    const int wv = n >> 6;        // wave 0..7
    const int ln = n & 63;        // lane

    if (n < 16) ((unsigned long long*)smask)[n] = 0ULL;

    // f64 column sum of r1 (ascending j) — recurrent term for a full spike mask
    double csum = 0.0;
    for (int j = 0; j < KIN; ++j)
        csum += (double)r1[(size_t)j * NRN + n];          // coalesced across n

    // neuron state in f64 (cheap: ~15 ops x 500 steps)
    double V = 1.0, Is = 0.0, Ir = 0.0, cnt = 0.0;
    const double steady = 0.01 * (double)n;
    constexpr double kS = 0.1;     // DT/TAU_SYN
    constexpr double kN = 0.05;    // DT/TAU_NEU
    constexpr double DT = 0.001;

    __syncthreads();

    for (int c = 0; c < NCH; ++c) {
        // ---- GEMM phase: acc[t] = sum_i x[t][i] * h1[i][n], f32, ascending i ----
        float acc[TCH];
        #pragma unroll
        for (int t = 0; t < TCH; ++t) acc[t] = 0.0f;

        for (int it = 0; it < KIN; it += 32) {            // runtime i-tile loop
            float hreg[32];
            #pragma unroll
            for (int k = 0; k < 32; ++k)
                hreg[k] = h1[(size_t)(it + k) * NRN + n]; // coalesced, L2-hot

            #pragma unroll
            for (int t = 0; t < TCH; ++t) {
                // wave-uniform address -> scalar loads (SMEM pipe), no LDS
                const float* __restrict__ xr =
                    x + ((size_t)(c * TCH + t) * BSZ + b) * KIN + it;
                #pragma unroll
                for (int k = 0; k < 32; ++k)
                    acc[t] = fmaf(xr[k], hreg[k], acc[t]);
            }
        }

        // ---- scan phase: TCH sequential steps, block-local spike exchange ----
        #pragma unroll
        for (int t = 0; t < TCH; ++t) {
            const int gt = c * TCH + t;
            const int p  = gt & 1;

            unsigned long long mw[8];
            int pc = 0;
            #pragma unroll
            for (int w = 0; w < 8; ++w) { mw[w] = smask[p][w]; pc += __popcll(mw[w]); }

            double aR;
            if (pc == 512) {
                aR = csum;                                 // dense ascending-j sum
            } else if (pc == 0) {
                aR = 0.0;
            } else {
                aR = 0.0;
                #pragma unroll
                for (int w = 0; w < 8; ++w) {
                    unsigned long long m = mw[w];
                    while (m) {                            // ascending j, uniform
                        const int j = w * 64 + __builtin_ctzll(m);
                        aR += (double)r1[(size_t)j * NRN + n];   // coalesced
                        m &= m - 1;
                    }
                }
            }

            Is = Is - kS * Is + (double)acc[t];            // gain_syn = 1
            Ir = Ir - kS * Ir + 0.5 * aR;                  // gain_syn_rec = 0.5
            double Vn = V - kN * V + DT * (Is + Ir + steady);
            Vn = fmax(Vn, 0.0);
            const bool sp = (Vn - 1.0) > 0.0;
            cnt = sp ? 2.0 : (cnt - 1.0);                  // REFR = 2
            V = sp ? 0.0 : ((cnt <= 0.0) ? Vn : 0.0);

            out[(size_t)gt * (BSZ * NRN) + (size_t)b * NRN + n] = sp ? 1.0f : 0.0f;

            const unsigned long long bal = __ballot(sp);
            if (ln == 0) smask[p ^ 1][wv] = bal;
            __syncthreads();
        }
    }
}

extern "C" void kernel_launch(void* const* d_in, const int* in_sizes, int n_in,
                              void* d_out, int out_size, void* d_ws, size_t ws_size,
                              hipStream_t stream) {
    const float* x  = (const float*)d_in[0];
    const float* h1 = (const float*)d_in[1];
    const float* r1 = (const float*)d_in[2];
    float* out = (float*)d_out;
    (void)d_ws; (void)ws_size; (void)in_sizes; (void)n_in; (void)out_size;

    lif_sim<<<dim3(BSZ), dim3(512), 0, stream>>>(x, h1, r1, out);
}

// Round 5
// 1111.225 us; speedup vs baseline: 6.7220x; 6.7220x over previous
//
#include <hip/hip_runtime.h>

// LIF sim, two-phase:
//   1) lif_gemm: aS[t][b][n] = x[t][b][:] @ h1[:][n]  (f32, ascending-i fmaf)
//      written into d_out (it has exactly T*BS*N f32 slots).
//   2) lif_scan: sequential 500-step LIF update per batch row (block-local),
//      reads aS from d_out, overwrites with spikes. f64 state, identical
//      decision path to the verified Round-3/4 kernels.
constexpr int BSZ = 256;
constexpr int NRN = 512;
constexpr int KIN = 512;
constexpr int TT  = 500;
constexpr int MT  = 32;               // GEMM rows per block (m = t*BSZ + b)

#define MAC8(r, xs, h0, h1v)                          \
    acc[r][0] = fmaf(xs, (h0).x,  acc[r][0]);         \
    acc[r][1] = fmaf(xs, (h0).y,  acc[r][1]);         \
    acc[r][2] = fmaf(xs, (h0).z,  acc[r][2]);         \
    acc[r][3] = fmaf(xs, (h0).w,  acc[r][3]);         \
    acc[r][4] = fmaf(xs, (h1v).x, acc[r][4]);         \
    acc[r][5] = fmaf(xs, (h1v).y, acc[r][5]);         \
    acc[r][6] = fmaf(xs, (h1v).z, acc[r][6]);         \
    acc[r][7] = fmaf(xs, (h1v).w, acc[r][7]);

__global__ __launch_bounds__(256, 2)
void lif_gemm(const float* __restrict__ x,
              const float* __restrict__ h1,
              float* __restrict__ out)
{
    __shared__ float xb[MT * KIN];          // 64 KB x-tile

    const int tid = threadIdx.x;
    const int mg  = tid >> 6;               // m-group 0..3 (8 rows each)
    const int n0  = (tid & 63) * 8;         // 8 contiguous output cols
    const size_t m0 = (size_t)blockIdx.x * MT;

    // stage 32 rows of x (64 KB contiguous), coalesced float4
    {
        const float4* src = reinterpret_cast<const float4*>(x + m0 * KIN);
        float4* dst = reinterpret_cast<float4*>(xb);
        #pragma unroll
        for (int it = 0; it < MT * KIN / 4 / 256; ++it)
            dst[it * 256 + tid] = src[it * 256 + tid];
    }
    __syncthreads();

    float acc[8][8];
    #pragma unroll
    for (int r = 0; r < 8; ++r)
        #pragma unroll
        for (int c = 0; c < 8; ++c) acc[r][c] = 0.0f;

    for (int k4 = 0; k4 < KIN / 4; ++k4) {
        float4 hv0[4], hv1[4];              // h1[4i][8n] micro-tile
        #pragma unroll
        for (int ii = 0; ii < 4; ++ii) {
            const float* hp = h1 + (size_t)(k4 * 4 + ii) * NRN + n0;
            hv0[ii] = *reinterpret_cast<const float4*>(hp);
            hv1[ii] = *reinterpret_cast<const float4*>(hp + 4);
        }
        #pragma unroll
        for (int r = 0; r < 8; ++r) {
            const float4 xv = *reinterpret_cast<const float4*>(
                &xb[(mg * 8 + r) * KIN + k4 * 4]);  // wave-broadcast LDS read
            MAC8(r, xv.x, hv0[0], hv1[0])           // ascending i
            MAC8(r, xv.y, hv0[1], hv1[1])
            MAC8(r, xv.z, hv0[2], hv1[2])
            MAC8(r, xv.w, hv0[3], hv1[3])
        }
    }

    #pragma unroll
    for (int r = 0; r < 8; ++r) {
        float* op = out + (m0 + mg * 8 + r) * NRN + n0;
        float4 o0 = { acc[r][0], acc[r][1], acc[r][2], acc[r][3] };
        float4 o1 = { acc[r][4], acc[r][5], acc[r][6], acc[r][7] };
        *reinterpret_cast<float4*>(op)     = o0;
        *reinterpret_cast<float4*>(op + 4) = o1;
    }
}

__global__ __launch_bounds__(512, 1)
void lif_scan(const float* __restrict__ r1,
              float* __restrict__ out)
{
    __shared__ unsigned long long smask[2][8];   // ping-pong 512-bit spike mask

    const int n  = threadIdx.x;      // neuron
    const int b  = blockIdx.x;       // batch row
    const int wv = n >> 6;
    const int ln = n & 63;
    const size_t row = (size_t)b * NRN + n;
    constexpr size_t STEP = (size_t)BSZ * NRN;

    if (n < 16) ((unsigned long long*)smask)[n] = 0ULL;

    // f64 ascending-j column sum of r1 (dense recurrent fast path)
    double csum = 0.0;
    for (int j = 0; j < KIN; ++j)
        csum += (double)r1[(size_t)j * NRN + n];

    double V = 1.0, Is = 0.0, Ir = 0.0, cnt = 0.0;
    const double steady = 0.01 * (double)n;
    constexpr double kS = 0.1, kN = 0.05, DT = 0.001;

    float aS = out[row];             // prefetched aS for t=0
    __syncthreads();

    for (int t = 0; t < TT; ++t) {
        const float aSn = (t + 1 < TT) ? out[(size_t)(t + 1) * STEP + row] : 0.0f;
        const int p = t & 1;

        unsigned long long mw[8];
        int pc = 0;
        #pragma unroll
        for (int w = 0; w < 8; ++w) { mw[w] = smask[p][w]; pc += __popcll(mw[w]); }

        double aR;
        if (pc == 512) {
            aR = csum;
        } else if (pc == 0) {
            aR = 0.0;
        } else {
            aR = 0.0;
            #pragma unroll
            for (int w = 0; w < 8; ++w) {
                unsigned long long m = mw[w];
                while (m) {                          // ascending j, block-uniform
                    const int j = w * 64 + __builtin_ctzll(m);
                    aR += (double)r1[(size_t)j * NRN + n];
                    m &= m - 1;
                }
            }
        }

        Is = Is - kS * Is + (double)aS;              // gain_syn = 1
        Ir = Ir - kS * Ir + 0.5 * aR;                // gain_syn_rec = 0.5
        double Vn = V - kN * V + DT * (Is + Ir + steady);
        Vn = fmax(Vn, 0.0);
        const bool sp = (Vn - 1.0) > 0.0;
        cnt = sp ? 2.0 : (cnt - 1.0);                // REFR = 2
        V = sp ? 0.0 : ((cnt <= 0.0) ? Vn : 0.0);

        out[(size_t)t * STEP + row] = sp ? 1.0f : 0.0f;

        const unsigned long long bal = __ballot(sp);
        if (ln == 0) smask[p ^ 1][wv] = bal;
        __syncthreads();
        aS = aSn;
    }
}

extern "C" void kernel_launch(void* const* d_in, const int* in_sizes, int n_in,
                              void* d_out, int out_size, void* d_ws, size_t ws_size,
                              hipStream_t stream) {
    const float* x  = (const float*)d_in[0];
    const float* h1 = (const float*)d_in[1];
    const float* r1 = (const float*)d_in[2];
    float* out = (float*)d_out;
    (void)d_ws; (void)ws_size; (void)in_sizes; (void)n_in; (void)out_size;

    lif_gemm<<<dim3(TT * BSZ / MT), dim3(256), 0, stream>>>(x, h1, out);
    lif_scan<<<dim3(BSZ), dim3(512), 0, stream>>>(r1, out);
}